// Round 1
// baseline (4636.460 us; speedup 1.0000x reference)
//
#include <hip/hip_runtime.h>
#include <math.h>

// RipsLayer: dim-0 persistence of Rips filtration on 4096 points in R^64.
// Phase 1: dense distance matrix D (64 MiB, in d_ws).
// Phase 2: exact Prim's MST replay (order-sensitive deaths) in one workgroup.

#define N 4096
#define DF 64

// ---------------------------------------------------------------------------
// Phase 1: D[i][j] = sqrt(max(|x_i - x_j|^2, 1e-12)), diag = +inf.
// Block = 256 threads computes a 64x64 output tile; K=64 staged fully in LDS.
// ---------------------------------------------------------------------------
__global__ __launch_bounds__(256) void build_d_kernel(const float* __restrict__ x,
                                                      float* __restrict__ D) {
    __shared__ float As[64][68];  // [row][k], +4 pad keeps 16B alignment, breaks pow2 stride
    __shared__ float Bs[64][68];
    const int bi = blockIdx.y * 64;
    const int bj = blockIdx.x * 64;
    const int t = threadIdx.x;

#pragma unroll
    for (int g = 0; g < 4; ++g) {
        int idx = t + 256 * g;           // 0..1023 float4 slots
        int row = idx >> 4;              // 64 rows, 16 float4 per row
        int k4 = (idx & 15) << 2;
        float4 va = *(const float4*)(x + (size_t)(bi + row) * DF + k4);
        float4 vb = *(const float4*)(x + (size_t)(bj + row) * DF + k4);
        *(float4*)(&As[row][k4]) = va;
        *(float4*)(&Bs[row][k4]) = vb;
    }
    __syncthreads();

    const int ti = (t >> 4) << 2;  // 4 output rows per thread
    const int tj = (t & 15) << 2;  // 4 output cols per thread

    float acc[4][4];
#pragma unroll
    for (int r = 0; r < 4; ++r)
#pragma unroll
        for (int c = 0; c < 4; ++c) acc[r][c] = 0.0f;

    for (int k = 0; k < 64; k += 4) {
        float4 a[4], b[4];
#pragma unroll
        for (int r = 0; r < 4; ++r) a[r] = *(const float4*)(&As[ti + r][k]);
#pragma unroll
        for (int c = 0; c < 4; ++c) b[c] = *(const float4*)(&Bs[tj + c][k]);
#pragma unroll
        for (int r = 0; r < 4; ++r)
#pragma unroll
            for (int c = 0; c < 4; ++c) {
                float d0 = a[r].x - b[c].x;
                float d1 = a[r].y - b[c].y;
                float d2 = a[r].z - b[c].z;
                float d3 = a[r].w - b[c].w;
                float s = acc[r][c];
                s = fmaf(d0, d0, s);
                s = fmaf(d1, d1, s);
                s = fmaf(d2, d2, s);
                s = fmaf(d3, d3, s);
                acc[r][c] = s;
            }
    }

#pragma unroll
    for (int r = 0; r < 4; ++r) {
        int i = bi + ti + r;
        float4 v;
        float* vp = &v.x;
#pragma unroll
        for (int c = 0; c < 4; ++c) {
            int j = bj + tj + c;
            vp[c] = (i == j) ? __builtin_huge_valf()
                             : sqrtf(fmaxf(acc[r][c], 1e-12f));
        }
        *(float4*)(D + (size_t)i * N + (bj + tj)) = v;  // coalesced float4 store
    }
}

// ---------------------------------------------------------------------------
// Phase 2: exact Prim replay. Single workgroup, 256 threads.
// Thread t owns columns {4t+1024g+l : g=0..3, l=0..3}; mind kept in registers.
// Argmin key = (float_bits << 32) | col  -> min gives lowest value, then
// lowest index on ties (matches jnp.argmin first-index semantics).
// ---------------------------------------------------------------------------
__global__ __launch_bounds__(256) void prim_kernel(const float* __restrict__ D,
                                                   float* __restrict__ out) {
    __shared__ unsigned long long partials[4];
    __shared__ int bcast;
    const int t = threadIdx.x;
    const int lane = t & 63;
    const int wave = t >> 6;

    float4 mind[4];
    unsigned mask = (t == 0) ? 1u : 0u;  // vertex 0 starts in tree (col 0 = t0,g0,l0)
#pragma unroll
    for (int g = 0; g < 4; ++g)
        mind[g] = ((const float4*)D)[t + 256 * g];  // row 0 of D

    for (int k = 0; k < N - 1; ++k) {
        // local masked argmin over this thread's 16 columns (increasing index)
        float bv = __builtin_huge_valf();
        int bj = N;
#pragma unroll
        for (int g = 0; g < 4; ++g) {
            const float* mp = (const float*)&mind[g];
#pragma unroll
            for (int l = 0; l < 4; ++l) {
                float v = ((mask >> ((g << 2) | l)) & 1u) ? __builtin_huge_valf()
                                                          : mp[l];
                int c = (t << 2) + (g << 10) + l;
                if (v < bv) { bv = v; bj = c; }
            }
        }
        unsigned long long key =
            ((unsigned long long)__float_as_uint(bv) << 32) | (unsigned)bj;

        // 64-lane wave reduction
#pragma unroll
        for (int off = 32; off > 0; off >>= 1) {
            unsigned long long o = __shfl_down(key, off, 64);
            key = (o < key) ? o : key;
        }
        if (lane == 0) partials[wave] = key;
        __syncthreads();
        if (t == 0) {
            unsigned long long kk = partials[0];
#pragma unroll
            for (int w = 1; w < 4; ++w) {
                unsigned long long o = partials[w];
                kk = (o < kk) ? o : kk;
            }
            out[2 * k] = 0.0f;                                   // birth
            out[2 * k + 1] = __uint_as_float((unsigned)(kk >> 32)); // death
            bcast = (int)(kk & 0xffffffffULL);
        }
        __syncthreads();
        const int j = bcast;

        // mark j in-tree (its owning thread flips the bit)
        if (((j >> 2) & 255) == t)
            mask |= 1u << ((((unsigned)j >> 10) << 2) | (j & 3));

        // mind = min(mind, D[j][:]) — one coalesced float4 per thread per group
        const float4* row = (const float4*)(D + (size_t)j * N);
#pragma unroll
        for (int g = 0; g < 4; ++g) {
            float4 r4 = row[t + 256 * g];
            mind[g].x = fminf(mind[g].x, r4.x);
            mind[g].y = fminf(mind[g].y, r4.y);
            mind[g].z = fminf(mind[g].z, r4.z);
            mind[g].w = fminf(mind[g].w, r4.w);
        }
    }
}

// ---------------------------------------------------------------------------
extern "C" void kernel_launch(void* const* d_in, const int* in_sizes, int n_in,
                              void* d_out, int out_size, void* d_ws, size_t ws_size,
                              hipStream_t stream) {
    const float* x = (const float*)d_in[0];
    float* D = (float*)d_ws;        // requires ws_size >= N*N*4 = 64 MiB
    float* out = (float*)d_out;     // [N-1][2] row-major: (birth=0, death)

    dim3 grid(N / 64, N / 64);
    build_d_kernel<<<grid, 256, 0, stream>>>(x, D);
    prim_kernel<<<1, 256, 0, stream>>>(D, out);
}